// Round 5
// baseline (397.299 us; speedup 1.0000x reference)
//
#include <hip/hip_runtime.h>
#include <stdint.h>
#include <stddef.h>

// MHA forward: B=4 T=2048 H=16 Dk=64 D=1024, fp32 in/out, fp16 MFMA internally.
// cvt weights -> fused QKV GEMM (in-kernel A cvt) -> pipelined flash attention -> output GEMM.

typedef __attribute__((ext_vector_type(4))) float f32x4;
typedef __attribute__((ext_vector_type(8))) _Float16 f16x8;
typedef __attribute__((ext_vector_type(4))) _Float16 f16x4;

#define DEV __device__ __forceinline__

constexpr int BATCH = 4, SEQ = 2048, NH = 16, DK = 64, DM = 1024;
constexpr int MROWS = BATCH * SEQ; // 8192
// log2-domain softmax: fold 1/sqrt(64) * log2(e) into Q projection
constexpr float QSCALE = 0.125f * 1.4426950408889634f;

DEV void async16(const void* g, void* l) {
  __builtin_amdgcn_global_load_lds(
      (const __attribute__((address_space(1))) unsigned int*)g,
      (__attribute__((address_space(3))) unsigned int*)l, 16, 0, 0);
}

// ---------------- weight fp32 -> fp16 ----------------
__global__ void cvt_w_kernel(const float* __restrict__ w0, const float* __restrict__ w1,
                             const float* __restrict__ w2, const float* __restrict__ w3,
                             _Float16* __restrict__ o0, _Float16* __restrict__ o1,
                             _Float16* __restrict__ o2, _Float16* __restrict__ o3) {
  size_t i = (size_t)blockIdx.x * blockDim.x + threadIdx.x;
  const float* ws[4] = {w0, w1, w2, w3};
  _Float16* os[4] = {o0, o1, o2, o3};
#pragma unroll
  for (int m = 0; m < 4; m++) {
    f32x4 x = *(const f32x4*)(ws[m] + i * 4);
    f16x4 h;
#pragma unroll
    for (int j = 0; j < 4; j++) h[j] = (_Float16)x[j];
    *(f16x4*)(os[m] + i * 4) = h;
  }
}

struct QKVPtrs {
  const float* a32[3];
  const _Float16* w[3];
  const float* bias[3];
  _Float16* out[3];
};

// ---------------- fused QKV GEMM: C = A[M,K] * W[N,K]^T + bias ----------------
// grid (m=64, n=8, z=3): same-m blocks ≡ same XCD -> A fetched once per XCD.
// A is fp32, converted to fp16 during LDS staging (no separate cvt pass).
// z=0: Q -> [B,H,T,64] (scaled by QSCALE); z=1: K -> [B,H,T,64]; z=2: V -> [B,H,64,T]
__global__ __launch_bounds__(256) void gemm_qkv_kernel(QKVPtrs P) {
  constexpr int K = DM;
  __shared__ __align__(16) _Float16 smem[128 * 144];
  _Float16* As = smem;
  _Float16* Bs = smem + 8192;
  const int z = blockIdx.z;
  const _Float16* Bw = P.w[z];
  const float* Af = P.a32[z];
  const int tid = threadIdx.x;
  const int wave = tid >> 6, lane = tid & 63;
  const int quad = lane >> 4, l16 = lane & 15;
  const int wm = wave >> 1, wn = wave & 1;
  const int m0 = blockIdx.x * 128, n0 = blockIdx.y * 128;
  const float scale = (z == 0) ? QSCALE : 1.0f;

  const f32x4 zero4 = {0.f, 0.f, 0.f, 0.f};
  f32x4 acc[4][4];
#pragma unroll
  for (int mt = 0; mt < 4; mt++)
#pragma unroll
    for (int nt = 0; nt < 4; nt++) acc[mt][nt] = zero4;

  float bv[4];
#pragma unroll
  for (int nt = 0; nt < 4; nt++) bv[nt] = P.bias[z][n0 + wn * 64 + nt * 16 + l16];

  for (int kt = 0; kt < K / 64; kt++) {
    const int k0 = kt * 64;
#pragma unroll
    for (int it = 0; it < 4; it++) {
      int idx = it * 256 + tid;
      async16(Bw + (size_t)(n0 + (idx >> 3)) * K + k0 + (idx & 7) * 8,
              (char*)Bs + (size_t)(it * 256 + wave * 64) * 16);
    }
#pragma unroll
    for (int it = 0; it < 4; it++) {
      int idx = it * 256 + tid;
      int row = idx >> 3, seg = idx & 7;
      const float* g = Af + (size_t)(m0 + row) * K + k0 + seg * 8;
      f32x4 x0 = *(const f32x4*)g;
      f32x4 x1 = *(const f32x4*)(g + 4);
      f16x8 h;
#pragma unroll
      for (int j = 0; j < 4; j++) { h[j] = (_Float16)x0[j]; h[4 + j] = (_Float16)x1[j]; }
      *(f16x8*)&As[row * 64 + seg * 8] = h;
    }
    __syncthreads();
#pragma unroll
    for (int ks = 0; ks < 2; ks++) {
      f16x8 af[4], bfr[4];
#pragma unroll
      for (int mt = 0; mt < 4; mt++)
        af[mt] = *(const f16x8*)&As[(wm * 64 + mt * 16 + l16) * 64 + ks * 32 + quad * 8];
#pragma unroll
      for (int nt = 0; nt < 4; nt++)
        bfr[nt] = *(const f16x8*)&Bs[(wn * 64 + nt * 16 + l16) * 64 + ks * 32 + quad * 8];
#pragma unroll
      for (int mt = 0; mt < 4; mt++)
#pragma unroll
        for (int nt = 0; nt < 4; nt++)
          acc[mt][nt] = __builtin_amdgcn_mfma_f32_16x16x32_f16(af[mt], bfr[nt], acc[mt][nt], 0, 0, 0);
    }
    __syncthreads();
  }

  // epilogue via LDS (stride 144), coalesced global stores
  _Float16* Ct = smem;
  const int b = m0 >> 11, tbase = m0 & (SEQ - 1);
  if (z < 2) {
#pragma unroll
    for (int mt = 0; mt < 4; mt++)
#pragma unroll
      for (int nt = 0; nt < 4; nt++)
#pragma unroll
        for (int i = 0; i < 4; i++)
          Ct[(wm * 64 + mt * 16 + quad * 4 + i) * 144 + wn * 64 + nt * 16 + l16] =
              (_Float16)((acc[mt][nt][i] + bv[nt]) * scale);
  } else {
#pragma unroll
    for (int mt = 0; mt < 4; mt++)
#pragma unroll
      for (int nt = 0; nt < 4; nt++)
#pragma unroll
        for (int i = 0; i < 4; i++)
          Ct[(wn * 64 + nt * 16 + l16) * 144 + wm * 64 + mt * 16 + quad * 4 + i] =
              (_Float16)(acc[mt][nt][i] + bv[nt]);
  }
  __syncthreads();
  _Float16* out = P.out[z];
  if (z < 2) {
    const int row = tid >> 1, coff = (tid & 1) * 32;
#pragma unroll
    for (int hh = 0; hh < 2; hh++) {
      int h = (n0 >> 6) + hh;
      size_t gb = ((size_t)(b * NH + h) * SEQ + tbase) * 64 + (size_t)tid * 32;
#pragma unroll
      for (int k2 = 0; k2 < 4; k2++)
        *(f16x8*)&out[gb + k2 * 8] =
            *(const f16x8*)&Ct[row * 144 + hh * 64 + coff + k2 * 8];
    }
  } else {
#pragma unroll
    for (int k2 = 0; k2 < 8; k2++) {
      int c = k2 * 256 + tid;
      int n = c >> 4, s2 = c & 15;
      int h = (n0 + n) >> 6, d = (n0 + n) & (DK - 1);
      size_t gb = ((size_t)(b * NH + h) * DK + d) * SEQ + tbase + s2 * 8;
      *(f16x8*)&out[gb] = *(const f16x8*)&Ct[n * 144 + s2 * 8];
    }
  }
}

// ---------------- output GEMM: fp16 A, fp32 out [M, DM]; grid (m=64, n=8) ----------------
__global__ __launch_bounds__(256) void gemm_out_kernel(
    const _Float16* __restrict__ Ah, const _Float16* __restrict__ Bw,
    const float* __restrict__ bias, float* __restrict__ Cp) {
  constexpr int K = DM;
  __shared__ __align__(16) _Float16 As[128 * 64];
  __shared__ __align__(16) _Float16 Bs[128 * 64];
  const int tid = threadIdx.x;
  const int wave = tid >> 6, lane = tid & 63;
  const int quad = lane >> 4, l16 = lane & 15;
  const int wm = wave >> 1, wn = wave & 1;
  const int m0 = blockIdx.x * 128, n0 = blockIdx.y * 128;

  const f32x4 zero4 = {0.f, 0.f, 0.f, 0.f};
  f32x4 acc[4][4];
#pragma unroll
  for (int mt = 0; mt < 4; mt++)
#pragma unroll
    for (int nt = 0; nt < 4; nt++) acc[mt][nt] = zero4;

  float bv[4];
#pragma unroll
  for (int nt = 0; nt < 4; nt++) bv[nt] = bias[n0 + wn * 64 + nt * 16 + l16];

  for (int kt = 0; kt < K / 64; kt++) {
    const int k0 = kt * 64;
#pragma unroll
    for (int it = 0; it < 4; it++) {
      int idx = it * 256 + tid;
      async16(Bw + (size_t)(n0 + (idx >> 3)) * K + k0 + (idx & 7) * 8,
              (char*)Bs + (size_t)(it * 256 + wave * 64) * 16);
    }
#pragma unroll
    for (int it = 0; it < 4; it++) {
      int idx = it * 256 + tid;
      async16(Ah + (size_t)(m0 + (idx >> 3)) * K + k0 + (idx & 7) * 8,
              (char*)As + (size_t)(it * 256 + wave * 64) * 16);
    }
    __syncthreads();
#pragma unroll
    for (int ks = 0; ks < 2; ks++) {
      f16x8 af[4], bfr[4];
#pragma unroll
      for (int mt = 0; mt < 4; mt++)
        af[mt] = *(const f16x8*)&As[(wm * 64 + mt * 16 + l16) * 64 + ks * 32 + quad * 8];
#pragma unroll
      for (int nt = 0; nt < 4; nt++)
        bfr[nt] = *(const f16x8*)&Bs[(wn * 64 + nt * 16 + l16) * 64 + ks * 32 + quad * 8];
#pragma unroll
      for (int mt = 0; mt < 4; mt++)
#pragma unroll
        for (int nt = 0; nt < 4; nt++)
          acc[mt][nt] = __builtin_amdgcn_mfma_f32_16x16x32_f16(af[mt], bfr[nt], acc[mt][nt], 0, 0, 0);
    }
    __syncthreads();
  }
#pragma unroll
  for (int mt = 0; mt < 4; mt++)
#pragma unroll
    for (int nt = 0; nt < 4; nt++)
#pragma unroll
      for (int i = 0; i < 4; i++) {
        int m = m0 + wm * 64 + mt * 16 + quad * 4 + i;
        int n = n0 + wn * 64 + nt * 16 + l16;
        Cp[(size_t)m * DM + n] = acc[mt][nt][i] + bv[nt];
      }
}

// ---------------- pipelined transposed-score flash attention (causal) ----------------
// grid (x=bh=64, y=pair=8): same-bh blocks ≡ same XCD -> K/V served from XCD-local L2.
// Double LDS buffers + register prefetch: one barrier per k-iter, global latency
// overlapped with compute. S^T via mfma(A=K,B=Q); PV A-frag comes free (k=quad*4+reg).
__global__ __launch_bounds__(256) void attn_kernel(
    const _Float16* __restrict__ Q, const _Float16* __restrict__ Kt,
    const _Float16* __restrict__ V, _Float16* __restrict__ O) {
  __shared__ __align__(16) _Float16 Ks[2][128 * 72];
  __shared__ __align__(16) _Float16 Vs[2][64 * 136];
  const int tid = threadIdx.x;
  const int wave = tid >> 6, lane = tid & 63, quad = lane >> 4, l16 = lane & 15;
  const int bh = blockIdx.x, xp = blockIdx.y;
  const size_t base = (size_t)bh * SEQ * DK;
  const int b = bh >> 4, h = bh & 15;
  const f32x4 zero4 = {0.f, 0.f, 0.f, 0.f};

  const int ck_row = tid >> 3, ck_off = (tid & 7) * 8;       // K-stage coords (c = tid, +256/iter)
  const int cv_d = tid >> 4, cv_off = (tid & 15) * 8;        // V-stage coords

  for (int p = 0; p < 2; p++) {
    const int qt = (p == 0) ? xp : 15 - xp;
    const int t0 = qt * 128;

    f16x8 qf[2][2];
#pragma unroll
    for (int mt = 0; mt < 2; mt++)
#pragma unroll
      for (int ks = 0; ks < 2; ks++)
        qf[mt][ks] = *(const f16x8*)(Q + base + (size_t)(t0 + wave * 32 + mt * 16 + l16) * DK +
                                     ks * 32 + quad * 8);

    // prefetch tile 0 into registers
    f16x8 kreg[4], vreg[4];
#pragma unroll
    for (int it = 0; it < 4; it++)
      kreg[it] = *(const f16x8*)(Kt + base + (size_t)(it * 32 + ck_row) * 64 + ck_off);
#pragma unroll
    for (int it = 0; it < 4; it++)
      vreg[it] = *(const f16x8*)(V + base + ((size_t)(it * 16 + cv_d) << 11) + cv_off);

    f32x4 oacc[2][4];
#pragma unroll
    for (int mt = 0; mt < 2; mt++)
#pragma unroll
      for (int nt = 0; nt < 4; nt++) oacc[mt][nt] = zero4;
    float mrow[2] = {-1e30f, -1e30f}, lrow[2] = {0.f, 0.f};

    for (int j = 0; j <= qt; j++) {
      const int buf = j & 1;
      _Float16* ksb = Ks[buf];
      _Float16* vsb = Vs[buf];
      // commit prefetched regs to LDS
#pragma unroll
      for (int it = 0; it < 4; it++)
        *(f16x8*)&ksb[(it * 32 + ck_row) * 72 + ck_off] = kreg[it];
#pragma unroll
      for (int it = 0; it < 4; it++)
        *(f16x8*)&vsb[(it * 16 + cv_d) * 136 + cv_off] = vreg[it];
      __syncthreads();
      // prefetch next tile (clamped reload of current on last iter — harmless, L2-hot)
      const int jn = (j < qt) ? j + 1 : qt;
#pragma unroll
      for (int it = 0; it < 4; it++)
        kreg[it] = *(const f16x8*)(Kt + base + (size_t)(jn * 128 + it * 32 + ck_row) * 64 + ck_off);
#pragma unroll
      for (int it = 0; it < 4; it++)
        vreg[it] = *(const f16x8*)(V + base + ((size_t)(it * 16 + cv_d) << 11) + jn * 128 + cv_off);

      // S^T frags: rows tk=quad*4+i (in nt*16 block), cols q=l16 (in wave*32+mt*16)
      f32x4 s[2][8];
#pragma unroll
      for (int nt = 0; nt < 8; nt++) {
        f16x8 kf0 = *(const f16x8*)&ksb[(nt * 16 + l16) * 72 + quad * 8];
        f16x8 kf1 = *(const f16x8*)&ksb[(nt * 16 + l16) * 72 + 32 + quad * 8];
#pragma unroll
        for (int mt = 0; mt < 2; mt++) {
          f32x4 zz = zero4;
          zz = __builtin_amdgcn_mfma_f32_16x16x32_f16(kf0, qf[mt][0], zz, 0, 0, 0);
          zz = __builtin_amdgcn_mfma_f32_16x16x32_f16(kf1, qf[mt][1], zz, 0, 0, 0);
          s[mt][nt] = zz;
        }
      }
      if (j == qt) { // diagonal: mask tk_local > q_local
#pragma unroll
        for (int mt = 0; mt < 2; mt++) {
          int qloc = wave * 32 + mt * 16 + l16;
#pragma unroll
          for (int nt = 0; nt < 8; nt++)
#pragma unroll
            for (int i = 0; i < 4; i++)
              if (nt * 16 + quad * 4 + i > qloc) s[mt][nt][i] = -1e30f;
        }
      }
      // online softmax: lane owns q=l16; 2 cross-quad shuffles per reduction
#pragma unroll
      for (int mt = 0; mt < 2; mt++) {
        float mx = mrow[mt];
#pragma unroll
        for (int nt = 0; nt < 8; nt++)
#pragma unroll
          for (int i = 0; i < 4; i++) mx = fmaxf(mx, s[mt][nt][i]);
        mx = fmaxf(mx, __shfl_xor(mx, 16));
        mx = fmaxf(mx, __shfl_xor(mx, 32));
        float alpha = __builtin_exp2f(mrow[mt] - mx);
        mrow[mt] = mx;
        float rs = 0.f;
#pragma unroll
        for (int nt = 0; nt < 8; nt++)
#pragma unroll
          for (int i = 0; i < 4; i++) {
            float pv = __builtin_exp2f(s[mt][nt][i] - mx);
            s[mt][nt][i] = pv;
            rs += pv;
          }
        rs += __shfl_xor(rs, 16);
        rs += __shfl_xor(rs, 32);
        lrow[mt] = lrow[mt] * alpha + rs;
#pragma unroll
        for (int i = 0; i < 4; i++) {
          float ab = __shfl(alpha, quad * 4 + i);
#pragma unroll
          for (int nt = 0; nt < 4; nt++) oacc[mt][nt][i] *= ab;
        }
      }
      // PV: A-frag = cvt(S^T frag) in regs; B-frag = Vs rows (d=l16), k=tk=quad*4+j
#pragma unroll
      for (int jj = 0; jj < 8; jj++) {
        f16x4 pf[2];
#pragma unroll
        for (int mt = 0; mt < 2; mt++) {
          f16x4 t;
#pragma unroll
          for (int i = 0; i < 4; i++) t[i] = (_Float16)s[mt][jj][i];
          pf[mt] = t;
        }
#pragma unroll
        for (int nt = 0; nt < 4; nt++) {
          f16x4 vb = *(const f16x4*)&vsb[(nt * 16 + l16) * 136 + jj * 16 + quad * 4];
#pragma unroll
          for (int mt = 0; mt < 2; mt++)
            oacc[mt][nt] = __builtin_amdgcn_mfma_f32_16x16x16f16(pf[mt], vb, oacc[mt][nt], 0, 0, 0);
        }
      }
      // no trailing barrier: next iter writes the other buffer; its barrier orders reuse
    }
    // epilogue: O rows q=quad*4+i, cols d=l16
#pragma unroll
    for (int mt = 0; mt < 2; mt++) {
      float linv = 1.0f / lrow[mt];
#pragma unroll
      for (int i = 0; i < 4; i++) {
        float lb = __shfl(linv, quad * 4 + i);
        int t = t0 + wave * 32 + mt * 16 + quad * 4 + i;
#pragma unroll
        for (int nt = 0; nt < 4; nt++) {
          int d = nt * 16 + l16;
          O[((size_t)(b * SEQ + t) << 10) + h * 64 + d] = (_Float16)(oacc[mt][nt][i] * lb);
        }
      }
    }
    __syncthreads(); // cross-pass parity guard: p=1's first ds_write may hit p=0's live buffer
  }
}

extern "C" void kernel_launch(void* const* d_in, const int* in_sizes, int n_in,
                              void* d_out, int out_size, void* d_ws, size_t ws_size,
                              hipStream_t stream) {
  const float* query = (const float*)d_in[0];
  const float* key_  = (const float*)d_in[1];
  const float* value = (const float*)d_in[2];
  const float* W_q = (const float*)d_in[4];
  const float* b_q = (const float*)d_in[5];
  const float* W_k = (const float*)d_in[6];
  const float* b_k = (const float*)d_in[7];
  const float* W_v = (const float*)d_in[8];
  const float* b_v = (const float*)d_in[9];
  const float* W_o = (const float*)d_in[10];
  const float* b_o = (const float*)d_in[11];

  constexpr size_t WEL = (size_t)DM * DM;    // 1M halves
  constexpr size_t MEL = (size_t)MROWS * DM; // 8M halves
  _Float16* ws = (_Float16*)d_ws;
  _Float16* wq = ws;
  _Float16* wk = wq + WEL;
  _Float16* wv = wk + WEL;
  _Float16* wo = wv + WEL;
  _Float16* qb = wo + WEL;
  _Float16* kb = qb + MEL;
  _Float16* vb = kb + MEL;
  _Float16* ab = vb + MEL; // total 72 MB

  cvt_w_kernel<<<dim3((unsigned)(WEL / 4 / 256)), 256, 0, stream>>>(
      W_q, W_k, W_v, W_o, wq, wk, wv, wo);

  QKVPtrs P;
  P.a32[0] = query; P.a32[1] = key_; P.a32[2] = value;
  P.w[0] = wq; P.w[1] = wk; P.w[2] = wv;
  P.bias[0] = b_q; P.bias[1] = b_k; P.bias[2] = b_v;
  P.out[0] = qb; P.out[1] = kb; P.out[2] = vb;
  gemm_qkv_kernel<<<dim3(MROWS / 128, DM / 128, 3), 256, 0, stream>>>(P);

  attn_kernel<<<dim3(BATCH * NH, 8), 256, 0, stream>>>(qb, kb, vb, ab);

  gemm_out_kernel<<<dim3(MROWS / 128, DM / 128), 256, 0, stream>>>(ab, wo, b_o, (float*)d_out);
}

// Round 6
// 389.715 us; speedup vs baseline: 1.0195x; 1.0195x over previous
//
#include <hip/hip_runtime.h>
#include <stdint.h>
#include <stddef.h>

// MHA forward: B=4 T=2048 H=16 Dk=64 D=1024, fp32 in/out, fp16 MFMA internally.
// fused cvt -> fused QKV GEMM (fp16 A, async16) -> transposed-score flash attention
// (XCD-local K/V) -> output GEMM.

typedef __attribute__((ext_vector_type(4))) float f32x4;
typedef __attribute__((ext_vector_type(8))) _Float16 f16x8;
typedef __attribute__((ext_vector_type(4))) _Float16 f16x4;

#define DEV __device__ __forceinline__

constexpr int BATCH = 4, SEQ = 2048, NH = 16, DK = 64, DM = 1024;
constexpr int MROWS = BATCH * SEQ; // 8192
// log2-domain softmax: fold 1/sqrt(64) * log2(e) into Q projection
constexpr float QSCALE = 0.125f * 1.4426950408889634f;

DEV void async16(const void* g, void* l) {
  __builtin_amdgcn_global_load_lds(
      (const __attribute__((address_space(1))) unsigned int*)g,
      (__attribute__((address_space(3))) unsigned int*)l, 16, 0, 0);
}

// ---------------- fused fp32 -> fp16 converter: 4 weight mats + 3 activations ----------------
struct CvtAll {
  const float* s[7];
  _Float16* d[7];
};
constexpr size_t WEL = (size_t)DM * DM;    // 1M elements per weight matrix
constexpr size_t MEL = (size_t)MROWS * DM; // 8M elements per activation
// float4 units: weights 4 * 2^18, acts 3 * 2^21; weight/act boundary = block 4096 exactly.
__global__ void cvt_all_kernel(CvtAll C) {
  size_t idx = (size_t)blockIdx.x * blockDim.x + threadIdx.x; // float4 index
  int m;
  size_t off;
  if (idx < 4 * (WEL / 4)) {
    m = (int)(idx >> 18);
    off = (idx & ((WEL / 4) - 1)) * 4;
  } else {
    size_t r = idx - 4 * (WEL / 4);
    m = 4 + (int)(r >> 21);
    off = (r & ((MEL / 4) - 1)) * 4;
  }
  f32x4 x = *(const f32x4*)(C.s[m] + off);
  f16x4 h;
#pragma unroll
  for (int j = 0; j < 4; j++) h[j] = (_Float16)x[j];
  *(f16x4*)(C.d[m] + off) = h;
}

struct QKVPtrs {
  const float* a32[3];
  const _Float16* a16[3];
  const _Float16* w[3];
  const float* bias[3];
  _Float16* out[3];
};

// ---------------- fused QKV GEMM: C = A[M,K] * W[N,K]^T + bias ----------------
// grid (m=64, n=8, z=3): same-m blocks ≡ same XCD -> A fetched ~once per XCD.
// z=0: Q -> [B,H,T,64] (scaled by QSCALE); z=1: K -> [B,H,T,64]; z=2: V -> [B,H,64,T]
template <bool AH>
__global__ __launch_bounds__(256) void gemm_qkv_kernel(QKVPtrs P) {
  constexpr int K = DM;
  __shared__ __align__(16) _Float16 smem[128 * 144];
  _Float16* As = smem;
  _Float16* Bs = smem + 8192;
  const int z = blockIdx.z;
  const _Float16* Bw = P.w[z];
  const int tid = threadIdx.x;
  const int wave = tid >> 6, lane = tid & 63;
  const int quad = lane >> 4, l16 = lane & 15;
  const int wm = wave >> 1, wn = wave & 1;
  const int m0 = blockIdx.x * 128, n0 = blockIdx.y * 128;
  const float scale = (z == 0) ? QSCALE : 1.0f;

  const f32x4 zero4 = {0.f, 0.f, 0.f, 0.f};
  f32x4 acc[4][4];
#pragma unroll
  for (int mt = 0; mt < 4; mt++)
#pragma unroll
    for (int nt = 0; nt < 4; nt++) acc[mt][nt] = zero4;

  float bv[4];
#pragma unroll
  for (int nt = 0; nt < 4; nt++) bv[nt] = P.bias[z][n0 + wn * 64 + nt * 16 + l16];

  for (int kt = 0; kt < K / 64; kt++) {
    const int k0 = kt * 64;
#pragma unroll
    for (int it = 0; it < 4; it++) {
      int idx = it * 256 + tid;
      async16(Bw + (size_t)(n0 + (idx >> 3)) * K + k0 + (idx & 7) * 8,
              (char*)Bs + (size_t)(it * 256 + wave * 64) * 16);
    }
    if (AH) {
      const _Float16* Af = P.a16[z];
#pragma unroll
      for (int it = 0; it < 4; it++) {
        int idx = it * 256 + tid;
        async16(Af + (size_t)(m0 + (idx >> 3)) * K + k0 + (idx & 7) * 8,
                (char*)As + (size_t)(it * 256 + wave * 64) * 16);
      }
    } else {
      const float* Af = P.a32[z];
#pragma unroll
      for (int it = 0; it < 4; it++) {
        int idx = it * 256 + tid;
        int row = idx >> 3, seg = idx & 7;
        const float* g = Af + (size_t)(m0 + row) * K + k0 + seg * 8;
        f32x4 x0 = *(const f32x4*)g;
        f32x4 x1 = *(const f32x4*)(g + 4);
        f16x8 h;
#pragma unroll
        for (int j = 0; j < 4; j++) { h[j] = (_Float16)x0[j]; h[4 + j] = (_Float16)x1[j]; }
        *(f16x8*)&As[row * 64 + seg * 8] = h;
      }
    }
    __syncthreads();
#pragma unroll
    for (int ks = 0; ks < 2; ks++) {
      f16x8 af[4], bfr[4];
#pragma unroll
      for (int mt = 0; mt < 4; mt++)
        af[mt] = *(const f16x8*)&As[(wm * 64 + mt * 16 + l16) * 64 + ks * 32 + quad * 8];
#pragma unroll
      for (int nt = 0; nt < 4; nt++)
        bfr[nt] = *(const f16x8*)&Bs[(wn * 64 + nt * 16 + l16) * 64 + ks * 32 + quad * 8];
#pragma unroll
      for (int mt = 0; mt < 4; mt++)
#pragma unroll
        for (int nt = 0; nt < 4; nt++)
          acc[mt][nt] = __builtin_amdgcn_mfma_f32_16x16x32_f16(af[mt], bfr[nt], acc[mt][nt], 0, 0, 0);
    }
    __syncthreads();
  }

  // epilogue via LDS (stride 144), coalesced global stores
  _Float16* Ct = smem;
  const int b = m0 >> 11, tbase = m0 & (SEQ - 1);
  if (z < 2) {
#pragma unroll
    for (int mt = 0; mt < 4; mt++)
#pragma unroll
      for (int nt = 0; nt < 4; nt++)
#pragma unroll
        for (int i = 0; i < 4; i++)
          Ct[(wm * 64 + mt * 16 + quad * 4 + i) * 144 + wn * 64 + nt * 16 + l16] =
              (_Float16)((acc[mt][nt][i] + bv[nt]) * scale);
  } else {
#pragma unroll
    for (int mt = 0; mt < 4; mt++)
#pragma unroll
      for (int nt = 0; nt < 4; nt++)
#pragma unroll
        for (int i = 0; i < 4; i++)
          Ct[(wn * 64 + nt * 16 + l16) * 144 + wm * 64 + mt * 16 + quad * 4 + i] =
              (_Float16)(acc[mt][nt][i] + bv[nt]);
  }
  __syncthreads();
  _Float16* out = P.out[z];
  if (z < 2) {
    const int row = tid >> 1, coff = (tid & 1) * 32;
#pragma unroll
    for (int hh = 0; hh < 2; hh++) {
      int h = (n0 >> 6) + hh;
      size_t gb = ((size_t)(b * NH + h) * SEQ + tbase) * 64 + (size_t)tid * 32;
#pragma unroll
      for (int k2 = 0; k2 < 4; k2++)
        *(f16x8*)&out[gb + k2 * 8] =
            *(const f16x8*)&Ct[row * 144 + hh * 64 + coff + k2 * 8];
    }
  } else {
#pragma unroll
    for (int k2 = 0; k2 < 8; k2++) {
      int c = k2 * 256 + tid;
      int n = c >> 4, s2 = c & 15;
      int h = (n0 + n) >> 6, d = (n0 + n) & (DK - 1);
      size_t gb = ((size_t)(b * NH + h) * DK + d) * SEQ + tbase + s2 * 8;
      *(f16x8*)&out[gb] = *(const f16x8*)&Ct[n * 144 + s2 * 8];
    }
  }
}

// ---------------- output GEMM: fp16 A, fp32 out [M, DM]; grid (m=64, n=8) ----------------
__global__ __launch_bounds__(256) void gemm_out_kernel(
    const _Float16* __restrict__ Ah, const _Float16* __restrict__ Bw,
    const float* __restrict__ bias, float* __restrict__ Cp) {
  constexpr int K = DM;
  __shared__ __align__(16) _Float16 As[128 * 64];
  __shared__ __align__(16) _Float16 Bs[128 * 64];
  const int tid = threadIdx.x;
  const int wave = tid >> 6, lane = tid & 63;
  const int quad = lane >> 4, l16 = lane & 15;
  const int wm = wave >> 1, wn = wave & 1;
  const int m0 = blockIdx.x * 128, n0 = blockIdx.y * 128;

  const f32x4 zero4 = {0.f, 0.f, 0.f, 0.f};
  f32x4 acc[4][4];
#pragma unroll
  for (int mt = 0; mt < 4; mt++)
#pragma unroll
    for (int nt = 0; nt < 4; nt++) acc[mt][nt] = zero4;

  float bv[4];
#pragma unroll
  for (int nt = 0; nt < 4; nt++) bv[nt] = bias[n0 + wn * 64 + nt * 16 + l16];

  for (int kt = 0; kt < K / 64; kt++) {
    const int k0 = kt * 64;
#pragma unroll
    for (int it = 0; it < 4; it++) {
      int idx = it * 256 + tid;
      async16(Bw + (size_t)(n0 + (idx >> 3)) * K + k0 + (idx & 7) * 8,
              (char*)Bs + (size_t)(it * 256 + wave * 64) * 16);
    }
#pragma unroll
    for (int it = 0; it < 4; it++) {
      int idx = it * 256 + tid;
      async16(Ah + (size_t)(m0 + (idx >> 3)) * K + k0 + (idx & 7) * 8,
              (char*)As + (size_t)(it * 256 + wave * 64) * 16);
    }
    __syncthreads();
#pragma unroll
    for (int ks = 0; ks < 2; ks++) {
      f16x8 af[4], bfr[4];
#pragma unroll
      for (int mt = 0; mt < 4; mt++)
        af[mt] = *(const f16x8*)&As[(wm * 64 + mt * 16 + l16) * 64 + ks * 32 + quad * 8];
#pragma unroll
      for (int nt = 0; nt < 4; nt++)
        bfr[nt] = *(const f16x8*)&Bs[(wn * 64 + nt * 16 + l16) * 64 + ks * 32 + quad * 8];
#pragma unroll
      for (int mt = 0; mt < 4; mt++)
#pragma unroll
        for (int nt = 0; nt < 4; nt++)
          acc[mt][nt] = __builtin_amdgcn_mfma_f32_16x16x32_f16(af[mt], bfr[nt], acc[mt][nt], 0, 0, 0);
    }
    __syncthreads();
  }
#pragma unroll
  for (int mt = 0; mt < 4; mt++)
#pragma unroll
    for (int nt = 0; nt < 4; nt++)
#pragma unroll
      for (int i = 0; i < 4; i++) {
        int m = m0 + wm * 64 + mt * 16 + quad * 4 + i;
        int n = n0 + wn * 64 + nt * 16 + l16;
        Cp[(size_t)m * DM + n] = acc[mt][nt][i] + bv[nt];
      }
}

// ---------------- transposed-score flash attention (causal) ----------------
// grid (x=bh=64, y=pair=8): same-bh blocks ≡ same XCD -> K/V (512 KB/bh, 4 MB/XCD)
// fetched once into XCD-local L2. Single-buffer 2-barrier body (explicit dbuf measured
// as a regression in R5). S^T = mfma(A=K,B=Q): lane owns q=l16 -> 2-shuffle reductions;
// S^T C-frag IS the PV A-frag of mfma_f32_16x16x16f16 -> no P LDS round-trip.
// Q,K: [B,H,T,64] fp16 (Q pre-scaled); V: [B,H,64,T] fp16; O: [B,T,H*64] fp16.
__global__ __launch_bounds__(256) void attn_kernel(
    const _Float16* __restrict__ Q, const _Float16* __restrict__ Kt,
    const _Float16* __restrict__ V, _Float16* __restrict__ O) {
  __shared__ __align__(16) _Float16 Ks[128 * 72];
  __shared__ __align__(16) _Float16 Vs[64 * 136];
  const int tid = threadIdx.x;
  const int wave = tid >> 6, lane = tid & 63, quad = lane >> 4, l16 = lane & 15;
  const int bh = blockIdx.x, xp = blockIdx.y;
  const size_t base = (size_t)bh * SEQ * DK;
  const int b = bh >> 4, h = bh & 15;
  const f32x4 zero4 = {0.f, 0.f, 0.f, 0.f};

  for (int p = 0; p < 2; p++) {
    const int qt = (p == 0) ? xp : 15 - xp;
    const int t0 = qt * 128;

    // Q-frags (B-operand): lane n=l16 -> q-row, k=d=quad*8+j
    f16x8 qf[2][2];
#pragma unroll
    for (int mt = 0; mt < 2; mt++)
#pragma unroll
      for (int ks = 0; ks < 2; ks++)
        qf[mt][ks] = *(const f16x8*)(Q + base + (size_t)(t0 + wave * 32 + mt * 16 + l16) * DK +
                                     ks * 32 + quad * 8);

    f32x4 oacc[2][4];
#pragma unroll
    for (int mt = 0; mt < 2; mt++)
#pragma unroll
      for (int nt = 0; nt < 4; nt++) oacc[mt][nt] = zero4;
    float mrow[2] = {-1e30f, -1e30f}, lrow[2] = {0.f, 0.f};

    for (int j = 0; j <= qt; j++) {
      // stage K [128 tk][64 d] -> Ks (stride 72), V [64 d][128 tk] -> Vs (stride 136)
#pragma unroll
      for (int it = 0; it < 4; it++) {
        int c = it * 256 + tid;
        int row = c >> 3, off = (c & 7) * 8;
        *(f16x8*)&Ks[row * 72 + off] =
            *(const f16x8*)(Kt + base + (size_t)(j * 128 + row) * 64 + off);
      }
#pragma unroll
      for (int it = 0; it < 4; it++) {
        int c = it * 256 + tid;
        int d = c >> 4, off = (c & 15) * 8;
        *(f16x8*)&Vs[d * 136 + off] =
            *(const f16x8*)(V + base + ((size_t)d << 11) + j * 128 + off);
      }
      __syncthreads();

      // S^T frags: rows tk=quad*4+i (in nt*16 block), cols q=l16 (in wave*32+mt*16)
      f32x4 s[2][8];
#pragma unroll
      for (int nt = 0; nt < 8; nt++) {
        f16x8 kf0 = *(const f16x8*)&Ks[(nt * 16 + l16) * 72 + quad * 8];
        f16x8 kf1 = *(const f16x8*)&Ks[(nt * 16 + l16) * 72 + 32 + quad * 8];
#pragma unroll
        for (int mt = 0; mt < 2; mt++) {
          f32x4 zz = zero4;
          zz = __builtin_amdgcn_mfma_f32_16x16x32_f16(kf0, qf[mt][0], zz, 0, 0, 0);
          zz = __builtin_amdgcn_mfma_f32_16x16x32_f16(kf1, qf[mt][1], zz, 0, 0, 0);
          s[mt][nt] = zz;
        }
      }
      if (j == qt) { // diagonal: mask tk_local > q_local
#pragma unroll
        for (int mt = 0; mt < 2; mt++) {
          int qloc = wave * 32 + mt * 16 + l16;
#pragma unroll
          for (int nt = 0; nt < 8; nt++)
#pragma unroll
            for (int i = 0; i < 4; i++)
              if (nt * 16 + quad * 4 + i > qloc) s[mt][nt][i] = -1e30f;
        }
      }
      // online softmax: lane owns q=l16; 2 cross-quad shuffles per reduction
#pragma unroll
      for (int mt = 0; mt < 2; mt++) {
        float mx = mrow[mt];
#pragma unroll
        for (int nt = 0; nt < 8; nt++)
#pragma unroll
          for (int i = 0; i < 4; i++) mx = fmaxf(mx, s[mt][nt][i]);
        mx = fmaxf(mx, __shfl_xor(mx, 16));
        mx = fmaxf(mx, __shfl_xor(mx, 32));
        float alpha = __builtin_exp2f(mrow[mt] - mx);
        mrow[mt] = mx;
        float rs = 0.f;
#pragma unroll
        for (int nt = 0; nt < 8; nt++)
#pragma unroll
          for (int i = 0; i < 4; i++) {
            float pv = __builtin_exp2f(s[mt][nt][i] - mx);
            s[mt][nt][i] = pv;
            rs += pv;
          }
        rs += __shfl_xor(rs, 16);
        rs += __shfl_xor(rs, 32);
        lrow[mt] = lrow[mt] * alpha + rs;
#pragma unroll
        for (int i = 0; i < 4; i++) {
          float ab = __shfl(alpha, quad * 4 + i);
#pragma unroll
          for (int nt = 0; nt < 4; nt++) oacc[mt][nt][i] *= ab;
        }
      }
      // PV: A-frag = cvt(S^T frag) in regs; B-frag = Vs rows (d=l16), k=tk=quad*4+j
#pragma unroll
      for (int jj = 0; jj < 8; jj++) {
        f16x4 pf[2];
#pragma unroll
        for (int mt = 0; mt < 2; mt++) {
          f16x4 t;
#pragma unroll
          for (int i = 0; i < 4; i++) t[i] = (_Float16)s[mt][jj][i];
          pf[mt] = t;
        }
#pragma unroll
        for (int nt = 0; nt < 4; nt++) {
          f16x4 vb = *(const f16x4*)&Vs[(nt * 16 + l16) * 136 + jj * 16 + quad * 4];
#pragma unroll
          for (int mt = 0; mt < 2; mt++)
            oacc[mt][nt] = __builtin_amdgcn_mfma_f32_16x16x16f16(pf[mt], vb, oacc[mt][nt], 0, 0, 0);
        }
      }
      __syncthreads();
    }
    // epilogue: O rows q=quad*4+i, cols d=l16
#pragma unroll
    for (int mt = 0; mt < 2; mt++) {
      float linv = 1.0f / lrow[mt];
#pragma unroll
      for (int i = 0; i < 4; i++) {
        float lb = __shfl(linv, quad * 4 + i);
        int t = t0 + wave * 32 + mt * 16 + quad * 4 + i;
#pragma unroll
        for (int nt = 0; nt < 4; nt++) {
          int d = nt * 16 + l16;
          O[((size_t)(b * SEQ + t) << 10) + h * 64 + d] = (_Float16)(oacc[mt][nt][i] * lb);
        }
      }
    }
  }
}

extern "C" void kernel_launch(void* const* d_in, const int* in_sizes, int n_in,
                              void* d_out, int out_size, void* d_ws, size_t ws_size,
                              hipStream_t stream) {
  const float* query = (const float*)d_in[0];
  const float* key_  = (const float*)d_in[1];
  const float* value = (const float*)d_in[2];
  const float* W_q = (const float*)d_in[4];
  const float* b_q = (const float*)d_in[5];
  const float* W_k = (const float*)d_in[6];
  const float* b_k = (const float*)d_in[7];
  const float* W_v = (const float*)d_in[8];
  const float* b_v = (const float*)d_in[9];
  const float* W_o = (const float*)d_in[10];
  const float* b_o = (const float*)d_in[11];

  _Float16* ws = (_Float16*)d_ws;
  _Float16* wq = ws;
  _Float16* wk = wq + WEL;
  _Float16* wv = wk + WEL;
  _Float16* wo = wv + WEL;

  // big layout: [weights 8MB][qh kh vh 48MB][qb kb vb 48MB]; ab overlays qh (dead by attn)
  const bool big = ws_size >= (size_t)(4 * WEL + 6 * MEL) * sizeof(_Float16);

  QKVPtrs P;
  P.a32[0] = query; P.a32[1] = key_; P.a32[2] = value;
  P.w[0] = wq; P.w[1] = wk; P.w[2] = wv;
  P.bias[0] = b_q; P.bias[1] = b_k; P.bias[2] = b_v;

  CvtAll C;
  C.s[0] = W_q; C.s[1] = W_k; C.s[2] = W_v; C.s[3] = W_o;
  C.d[0] = wq;  C.d[1] = wk;  C.d[2] = wv;  C.d[3] = wo;

  _Float16 *qb, *kb, *vb, *ab;
  if (big) {
    _Float16* qh = wo + WEL;
    _Float16* kh = qh + MEL;
    _Float16* vh = kh + MEL;
    qb = vh + MEL; kb = qb + MEL; vb = kb + MEL;
    ab = qh; // reuse: q-act copy dead once qkv GEMM finishes
    C.s[4] = query; C.s[5] = key_; C.s[6] = value;
    C.d[4] = qh;    C.d[5] = kh;   C.d[6] = vh;
    P.a16[0] = qh; P.a16[1] = kh; P.a16[2] = vh;
    P.out[0] = qb; P.out[1] = kb; P.out[2] = vb;
    // weights: 4*WEL/4 f4 -> 4096 blocks; acts: 3*MEL/4 f4 -> 24576 blocks
    cvt_all_kernel<<<dim3((unsigned)((4 * (WEL / 4) + 3 * (MEL / 4)) / 256)), 256, 0, stream>>>(C);
    gemm_qkv_kernel<true><<<dim3(MROWS / 128, DM / 128, 3), 256, 0, stream>>>(P);
  } else {
    qb = wo + WEL; kb = qb + MEL; vb = kb + MEL; ab = vb + MEL;
    C.s[4] = C.s[5] = C.s[6] = W_q; // unused by weight-only grid
    C.d[4] = C.d[5] = C.d[6] = wq;
    P.a16[0] = P.a16[1] = P.a16[2] = nullptr;
    P.out[0] = qb; P.out[1] = kb; P.out[2] = vb;
    cvt_all_kernel<<<dim3((unsigned)(4 * (WEL / 4) / 256)), 256, 0, stream>>>(C);
    gemm_qkv_kernel<false><<<dim3(MROWS / 128, DM / 128, 3), 256, 0, stream>>>(P);
  }

  attn_kernel<<<dim3(BATCH * NH, 8), 256, 0, stream>>>(qb, kb, vb, ab);

  gemm_out_kernel<<<dim3(MROWS / 128, DM / 128), 256, 0, stream>>>(ab, wo, b_o, (float*)d_out);
}